// Round 1
// baseline (276.218 us; speedup 1.0000x reference)
//
#include <hip/hip_runtime.h>
#include <hip/hip_bf16.h>

#define N_NODES 4096
#define IN_DIM 1024
#define OUT_DIM 512
#define NUM_HEADS 4
#define HEAD_DIM 128
#define TOP_K 16
#define NEG_SLOPE 0.2f

typedef __attribute__((ext_vector_type(8))) short bf16x8;
typedef __attribute__((ext_vector_type(4))) float f32x4;

__device__ __forceinline__ unsigned short f2bf(float f) {
    unsigned u = __float_as_uint(f);
    unsigned r = u + 0x7FFFu + ((u >> 16) & 1u);   // round-to-nearest-even
    return (unsigned short)(r >> 16);
}
__device__ __forceinline__ float bf2f(unsigned short h) {
    return __uint_as_float(((unsigned)h) << 16);
}

// ---------------------------------------------------------------------------
// GEMM: Wh[4096][512] = x[4096][1024] @ W[512][1024]^T  (split-bf16 MFMA)
// Tile 128x64, BK=32, 4 waves (2x2), each wave 64x32 -> 4x2 frags of 16x16.
// ---------------------------------------------------------------------------
#define BM 128
#define BN 64
#define BK 32
#define LDP 40   // padded LDS row (bf16 elems): 80B stride -> spread banks

__global__ __launch_bounds__(256) void gemm_split_kernel(
    const float* __restrict__ x, const float* __restrict__ W, float* __restrict__ Wh)
{
    __shared__ __align__(16) unsigned short Ah[BM * LDP];
    __shared__ __align__(16) unsigned short Al[BM * LDP];
    __shared__ __align__(16) unsigned short Bh[BN * LDP];
    __shared__ __align__(16) unsigned short Bl[BN * LDP];

    const int tid  = threadIdx.x;
    const int bm   = blockIdx.x, bn = blockIdx.y;
    const int wave = tid >> 6,   lane = tid & 63;
    const int lr   = lane & 15,  lk = lane >> 4;
    const int m0   = (wave & 1) * 64;
    const int n0   = (wave >> 1) * 32;

    f32x4 acc[4][2];
#pragma unroll
    for (int i = 0; i < 4; ++i)
#pragma unroll
        for (int j = 0; j < 2; ++j) acc[i][j] = (f32x4){0.f, 0.f, 0.f, 0.f};

    for (int kt = 0; kt < IN_DIM / BK; ++kt) {
        // ---- stage A tile: 128x32 f32 = 1024 float4, 4 per thread ----
#pragma unroll
        for (int i = 0; i < 4; ++i) {
            int f4  = i * 256 + tid;
            int row = f4 >> 3, kq = f4 & 7;
            float4 v = *(const float4*)(x + (size_t)(bm * BM + row) * IN_DIM + kt * BK + kq * 4);
            unsigned short h0 = f2bf(v.x), h1 = f2bf(v.y), h2 = f2bf(v.z), h3 = f2bf(v.w);
            unsigned short l0 = f2bf(v.x - bf2f(h0)), l1 = f2bf(v.y - bf2f(h1));
            unsigned short l2 = f2bf(v.z - bf2f(h2)), l3 = f2bf(v.w - bf2f(h3));
            *(ushort4*)&Ah[row * LDP + kq * 4] = make_ushort4(h0, h1, h2, h3);
            *(ushort4*)&Al[row * LDP + kq * 4] = make_ushort4(l0, l1, l2, l3);
        }
        // ---- stage B tile: 64x32 f32 = 512 float4, 2 per thread ----
#pragma unroll
        for (int i = 0; i < 2; ++i) {
            int f4  = i * 256 + tid;
            int row = f4 >> 3, kq = f4 & 7;
            float4 v = *(const float4*)(W + (size_t)(bn * BN + row) * IN_DIM + kt * BK + kq * 4);
            unsigned short h0 = f2bf(v.x), h1 = f2bf(v.y), h2 = f2bf(v.z), h3 = f2bf(v.w);
            unsigned short l0 = f2bf(v.x - bf2f(h0)), l1 = f2bf(v.y - bf2f(h1));
            unsigned short l2 = f2bf(v.z - bf2f(h2)), l3 = f2bf(v.w - bf2f(h3));
            *(ushort4*)&Bh[row * LDP + kq * 4] = make_ushort4(h0, h1, h2, h3);
            *(ushort4*)&Bl[row * LDP + kq * 4] = make_ushort4(l0, l1, l2, l3);
        }
        __syncthreads();

        bf16x8 ah[4], al[4], bh[2], bl[2];
#pragma unroll
        for (int mi = 0; mi < 4; ++mi) {
            int r = m0 + mi * 16 + lr;
            ah[mi] = *(const bf16x8*)&Ah[r * LDP + lk * 8];
            al[mi] = *(const bf16x8*)&Al[r * LDP + lk * 8];
        }
#pragma unroll
        for (int ni = 0; ni < 2; ++ni) {
            int r = n0 + ni * 16 + lr;
            bh[ni] = *(const bf16x8*)&Bh[r * LDP + lk * 8];
            bl[ni] = *(const bf16x8*)&Bl[r * LDP + lk * 8];
        }
#pragma unroll
        for (int mi = 0; mi < 4; ++mi)
#pragma unroll
            for (int ni = 0; ni < 2; ++ni) {
                acc[mi][ni] = __builtin_amdgcn_mfma_f32_16x16x32_bf16(ah[mi], bh[ni], acc[mi][ni], 0, 0, 0);
                acc[mi][ni] = __builtin_amdgcn_mfma_f32_16x16x32_bf16(ah[mi], bl[ni], acc[mi][ni], 0, 0, 0);
                acc[mi][ni] = __builtin_amdgcn_mfma_f32_16x16x32_bf16(al[mi], bh[ni], acc[mi][ni], 0, 0, 0);
            }
        __syncthreads();
    }

    // epilogue: D row = lk*4 + r (reg), col = lr
#pragma unroll
    for (int mi = 0; mi < 4; ++mi)
#pragma unroll
        for (int ni = 0; ni < 2; ++ni)
#pragma unroll
            for (int r = 0; r < 4; ++r) {
                int row_g = bm * BM + m0 + mi * 16 + lk * 4 + r;
                int col_g = bn * BN + n0 + ni * 16 + lr;
                Wh[(size_t)row_g * OUT_DIM + col_g] = acc[mi][ni][r];
            }
}

// ---------------------------------------------------------------------------
// Scores: s_src[n][h] = Wh[n,h,:]·a[:128], s_dst[n][h] = Wh[n,h,:]·a[128:]
// One wave per (n, h): grid 4096, block 256 (wave = head).
// ---------------------------------------------------------------------------
__global__ __launch_bounds__(256) void score_kernel(
    const float* __restrict__ Wh, const float* __restrict__ a,
    float* __restrict__ s_src, float* __restrict__ s_dst)
{
    const int n = blockIdx.x;
    const int h = threadIdx.x >> 6, lane = threadIdx.x & 63;
    const float* whp = Wh + (size_t)n * OUT_DIM + h * HEAD_DIM;
    float ss = 0.f, sd = 0.f;
#pragma unroll
    for (int i = 0; i < 2; ++i) {
        int d = lane + i * 64;
        float w = whp[d];
        ss += w * a[d];
        sd += w * a[HEAD_DIM + d];
    }
#pragma unroll
    for (int m = 1; m < 64; m <<= 1) {
        ss += __shfl_xor(ss, m);
        sd += __shfl_xor(sd, m);
    }
    if (lane == 0) {
        s_src[n * NUM_HEADS + h] = ss;
        s_dst[n * NUM_HEADS + h] = sd;
    }
}

// ---------------------------------------------------------------------------
// Top-16 per adj row. One wave per row, 64 f32/lane in registers,
// 16 iterative wave-argmax rounds, tie-break lowest index (lax.top_k).
// ---------------------------------------------------------------------------
__global__ __launch_bounds__(256) void topk_kernel(
    const float* __restrict__ adj, int* __restrict__ topk)
{
    const int wave = threadIdx.x >> 6, lane = threadIdx.x & 63;
    const int row  = blockIdx.x * 4 + wave;
    const float* rp = adj + (size_t)row * N_NODES;

    float v[64];
#pragma unroll
    for (int i = 0; i < 16; ++i) {
        float4 q = *(const float4*)(rp + i * 256 + lane * 4);
        v[i * 4 + 0] = q.x; v[i * 4 + 1] = q.y; v[i * 4 + 2] = q.z; v[i * 4 + 3] = q.w;
    }
    int* op = topk + (size_t)row * TOP_K;

    for (int r = 0; r < TOP_K; ++r) {
        float bv = -INFINITY; int bg = 0x7fffffff;
#pragma unroll
        for (int s = 0; s < 64; ++s) {
            int g = (s >> 2) * 256 + lane * 4 + (s & 3);
            bool better = (v[s] > bv) || (v[s] == bv && g < bg);
            bv = better ? v[s] : bv;
            bg = better ? g : bg;
        }
#pragma unroll
        for (int m = 1; m < 64; m <<= 1) {
            float ov = __shfl_xor(bv, m);
            int   og = __shfl_xor(bg, m);
            bool better = (ov > bv) || (ov == bv && og < bg);
            bv = better ? ov : bv;
            bg = better ? og : bg;
        }
        if (lane == 0) op[r] = bg;
#pragma unroll
        for (int s = 0; s < 64; ++s) {      // static-index invalidation (no scratch)
            int g = (s >> 2) * 256 + lane * 4 + (s & 3);
            if (g == bg) v[s] = -INFINITY;
        }
    }
}

// ---------------------------------------------------------------------------
// Aggregate: per row i -> leaky_relu scores over 16 nbrs, softmax per head,
// out[i, h*128+d] = elu( sum_m alpha[m][h] * Wh[idx_m, h*128+d] )
// ---------------------------------------------------------------------------
__global__ __launch_bounds__(256) void aggregate_kernel(
    const float* __restrict__ Wh, const int* __restrict__ topk,
    const float* __restrict__ s_src, const float* __restrict__ s_dst,
    float* __restrict__ out)
{
    const int i = blockIdx.x, t = threadIdx.x;
    __shared__ int   sidx[TOP_K];
    __shared__ float salpha[TOP_K][NUM_HEADS];
    __shared__ float ssrc[NUM_HEADS];

    if (t < TOP_K) sidx[t] = topk[(size_t)i * TOP_K + t];
    if (t < NUM_HEADS) ssrc[t] = s_src[i * NUM_HEADS + t];
    __syncthreads();

    if (t < TOP_K * NUM_HEADS) {
        int m = t >> 2, h = t & 3;
        float e = ssrc[h] + s_dst[sidx[m] * NUM_HEADS + h];
        e = (e >= 0.f) ? e : NEG_SLOPE * e;
        salpha[m][h] = e;
    }
    __syncthreads();

    if (t < NUM_HEADS) {
        int h = t;
        float mx = -INFINITY;
#pragma unroll
        for (int m = 0; m < TOP_K; ++m) mx = fmaxf(mx, salpha[m][h]);
        float ex[TOP_K]; float sum = 0.f;
#pragma unroll
        for (int m = 0; m < TOP_K; ++m) { ex[m] = expf(salpha[m][h] - mx); sum += ex[m]; }
        float inv = 1.f / sum;
#pragma unroll
        for (int m = 0; m < TOP_K; ++m) salpha[m][h] = ex[m] * inv;
    }
    __syncthreads();

#pragma unroll
    for (int rep = 0; rep < 2; ++rep) {
        int c = rep * 256 + t;          // c = h*128 + d
        int h = c >> 7;
        float acc = 0.f;
#pragma unroll
        for (int m = 0; m < TOP_K; ++m)
            acc += salpha[m][h] * Wh[(size_t)sidx[m] * OUT_DIM + c];
        out[(size_t)i * OUT_DIM + c] = (acc > 0.f) ? acc : (expf(acc) - 1.f);
    }
}

// ---------------------------------------------------------------------------
extern "C" void kernel_launch(void* const* d_in, const int* in_sizes, int n_in,
                              void* d_out, int out_size, void* d_ws, size_t ws_size,
                              hipStream_t stream) {
    const float* x   = (const float*)d_in[0];
    const float* adj = (const float*)d_in[1];
    const float* W   = (const float*)d_in[2];
    const float* a   = (const float*)d_in[3];
    float* out = (float*)d_out;

    char* ws = (char*)d_ws;
    float* Wh    = (float*)ws;                                   // 4096*512*4 = 8 MB
    float* s_src = (float*)(ws + (size_t)N_NODES * OUT_DIM * 4); // 64 KB
    float* s_dst = s_src + N_NODES * NUM_HEADS;                  // 64 KB
    int*   topk  = (int*)(s_dst + N_NODES * NUM_HEADS);          // 256 KB

    gemm_split_kernel<<<dim3(N_NODES / BM, OUT_DIM / BN), 256, 0, stream>>>(x, W, Wh);
    score_kernel<<<N_NODES, 256, 0, stream>>>(Wh, a, s_src, s_dst);
    topk_kernel<<<N_NODES / 4, 256, 0, stream>>>(adj, topk);
    aggregate_kernel<<<N_NODES, 256, 0, stream>>>(Wh, topk, s_src, s_dst, out);
}

// Round 2
// 174.071 us; speedup vs baseline: 1.5868x; 1.5868x over previous
//
#include <hip/hip_runtime.h>
#include <hip/hip_bf16.h>

#define N_NODES 4096
#define IN_DIM 1024
#define OUT_DIM 512
#define NUM_HEADS 4
#define HEAD_DIM 128
#define TOP_K 16
#define NEG_SLOPE 0.2f

typedef __attribute__((ext_vector_type(8))) short bf16x8;
typedef __attribute__((ext_vector_type(4))) float f32x4;

typedef __attribute__((address_space(3))) unsigned as3_u32;
typedef const __attribute__((address_space(1))) unsigned as1_u32;

static __device__ __forceinline__ void gld16(const void* g, void* l) {
    __builtin_amdgcn_global_load_lds((as1_u32*)g, (as3_u32*)l, 16, 0, 0);
}

__device__ __forceinline__ unsigned short f2bf(float f) {
    unsigned u = __float_as_uint(f);
    unsigned r = u + 0x7FFFu + ((u >> 16) & 1u);   // round-to-nearest-even
    return (unsigned short)(r >> 16);
}
__device__ __forceinline__ float bf2f(unsigned short h) {
    return __uint_as_float(((unsigned)h) << 16);
}

// ---------------------------------------------------------------------------
// Prep: f32 [rows][1024] -> combined hi|lo bf16, pre-swizzled for GEMM LDS.
// Per row, per 32-elem k-block: 8 chunks of 16B = {hi c=0..3, lo c=4..7},
// chunk stored at position c ^ (row & 7).  Row stride = 2048 ushorts.
// One thread per (row, kb, c<4): reads 8 f32, writes hi-chunk + lo-chunk.
// ---------------------------------------------------------------------------
__global__ __launch_bounds__(256) void prep_kernel(
    const float* __restrict__ src, unsigned short* __restrict__ dst)
{
    int t = blockIdx.x * 256 + threadIdx.x;     // t = row*128 + kb*4 + c
    int row = t >> 7, rem = t & 127, kb = rem >> 2, c = rem & 3;
    const float* s = src + (size_t)row * IN_DIM + kb * 32 + c * 8;
    float4 v0 = *(const float4*)s;
    float4 v1 = *(const float4*)(s + 4);
    float vv[8] = {v0.x, v0.y, v0.z, v0.w, v1.x, v1.y, v1.z, v1.w};
    bf16x8 H, L;
#pragma unroll
    for (int e = 0; e < 8; ++e) {
        unsigned short h = f2bf(vv[e]);
        H[e] = (short)h;
        L[e] = (short)f2bf(vv[e] - bf2f(h));
    }
    int sw = row & 7;
    unsigned short* base = dst + (size_t)row * 2048 + kb * 64;
    *(bf16x8*)(base + ((c ^ sw) << 3))       = H;
    *(bf16x8*)(base + (((c + 4) ^ sw) << 3)) = L;
}

// ---------------------------------------------------------------------------
// GEMM: Wh = x @ W^T via split-bf16 (hh + hl + lh), pre-converted inputs.
// Tile 128x64, BK=32, 512 threads = 8 waves (2m x 4n), wave-tile 64x16.
// LDS double-buffered; staging via global_load_lds(16B) from swizzled src.
// ---------------------------------------------------------------------------
#define GBM 128
#define GBN 64
#define NT  (IN_DIM / 32)    // 32 K-steps

__global__ __launch_bounds__(512) void gemm_kernel(
    const unsigned short* __restrict__ xc, const unsigned short* __restrict__ wc,
    float* __restrict__ Wh)
{
    __shared__ __align__(16) unsigned short As[2][GBM * 64];  // 16 KB each
    __shared__ __align__(16) unsigned short Bs[2][GBN * 64];  //  8 KB each

    const int tid  = threadIdx.x;
    const int bm   = blockIdx.x, bn = blockIdx.y;
    const int wave = tid >> 6,   lane = tid & 63;
    const int wm   = wave >> 2,  wn = wave & 3;      // 2 x 4 wave grid
    const int lr   = lane & 15,  lk = lane >> 4;

    f32x4 acc[4];
#pragma unroll
    for (int i = 0; i < 4; ++i) acc[i] = (f32x4){0.f, 0.f, 0.f, 0.f};

    auto stage = [&](int buf, int kt) {
#pragma unroll
        for (int seg = 0; seg < 2; ++seg) {          // A: 16 KB = 1024 chunks
            int ci = seg * 512 + tid;
            int row = ci >> 3, p = ci & 7;
            const char* src = (const char*)xc +
                ((size_t)(bm * GBM + row) * 4096 + (size_t)kt * 128 + p * 16);
            gld16(src, (char*)&As[buf][0] + (size_t)ci * 16);
        }
        {                                            // B: 8 KB = 512 chunks
            int ci = tid;
            int row = ci >> 3, p = ci & 7;
            const char* src = (const char*)wc +
                ((size_t)(bn * GBN + row) * 4096 + (size_t)kt * 128 + p * 16);
            gld16(src, (char*)&Bs[buf][0] + (size_t)ci * 16);
        }
    };

    stage(0, 0);
    __syncthreads();
    int cur = 0;
    for (int kt = 0; kt < NT; ++kt) {
        if (kt + 1 < NT) stage(cur ^ 1, kt + 1);

        bf16x8 bh, bl;
        {
            int rb = wn * 16 + lr, sw = (rb & 7) << 3;
            bh = *(const bf16x8*)&Bs[cur][rb * 64 + ((lk * 8) ^ sw)];
            bl = *(const bf16x8*)&Bs[cur][rb * 64 + ((32 + lk * 8) ^ sw)];
        }
#pragma unroll
        for (int mi = 0; mi < 4; ++mi) {
            int r = wm * 64 + mi * 16 + lr, sw = (r & 7) << 3;
            bf16x8 ah = *(const bf16x8*)&As[cur][r * 64 + ((lk * 8) ^ sw)];
            bf16x8 al = *(const bf16x8*)&As[cur][r * 64 + ((32 + lk * 8) ^ sw)];
            acc[mi] = __builtin_amdgcn_mfma_f32_16x16x32_bf16(ah, bh, acc[mi], 0, 0, 0);
            acc[mi] = __builtin_amdgcn_mfma_f32_16x16x32_bf16(ah, bl, acc[mi], 0, 0, 0);
            acc[mi] = __builtin_amdgcn_mfma_f32_16x16x32_bf16(al, bh, acc[mi], 0, 0, 0);
        }
        __syncthreads();   // drains vmcnt (next buf staged) + frees cur buf
        cur ^= 1;
    }

#pragma unroll
    for (int mi = 0; mi < 4; ++mi)
#pragma unroll
        for (int r = 0; r < 4; ++r) {
            int row_g = bm * GBM + wm * 64 + mi * 16 + lk * 4 + r;
            int col_g = bn * GBN + wn * 16 + lr;
            Wh[(size_t)row_g * OUT_DIM + col_g] = acc[mi][r];
        }
}

// ---------------------------------------------------------------------------
// Scores: s_src[n][h] = Wh[n,h,:]·a[:128], s_dst[n][h] = Wh[n,h,:]·a[128:]
// ---------------------------------------------------------------------------
__global__ __launch_bounds__(256) void score_kernel(
    const float* __restrict__ Wh, const float* __restrict__ a,
    float* __restrict__ s_src, float* __restrict__ s_dst)
{
    const int n = blockIdx.x;
    const int h = threadIdx.x >> 6, lane = threadIdx.x & 63;
    const float* whp = Wh + (size_t)n * OUT_DIM + h * HEAD_DIM;
    float ss = 0.f, sd = 0.f;
#pragma unroll
    for (int i = 0; i < 2; ++i) {
        int d = lane + i * 64;
        float w = whp[d];
        ss += w * a[d];
        sd += w * a[HEAD_DIM + d];
    }
#pragma unroll
    for (int m = 1; m < 64; m <<= 1) {
        ss += __shfl_xor(ss, m);
        sd += __shfl_xor(sd, m);
    }
    if (lane == 0) {
        s_src[n * NUM_HEADS + h] = ss;
        s_dst[n * NUM_HEADS + h] = sd;
    }
}

// ---------------------------------------------------------------------------
// Top-16 per adj row.  Fast path: threshold-filter (~49 of 4096 expected),
// compact candidates as packed u64 keys (value-orderable | inverted index)
// into LDS, then 16 wave-argmax rounds over <=2 keys/lane.  Exact fallback
// (full 16-round scan) if count outside [16, 128].
// ---------------------------------------------------------------------------
#define TK_THRESH 0.988f
#define TK_CAP 128

__global__ __launch_bounds__(256) void topk_kernel(
    const float* __restrict__ adj, int* __restrict__ topk)
{
    const int wave = threadIdx.x >> 6, lane = threadIdx.x & 63;
    const int row  = blockIdx.x * 4 + wave;
    const float* rp = adj + (size_t)row * N_NODES;
    __shared__ unsigned long long cand[4][TK_CAP];

    float v[64];
#pragma unroll
    for (int i = 0; i < 16; ++i) {
        float4 q = *(const float4*)(rp + i * 256 + lane * 4);
        v[i * 4 + 0] = q.x; v[i * 4 + 1] = q.y; v[i * 4 + 2] = q.z; v[i * 4 + 3] = q.w;
    }
    int* op = topk + (size_t)row * TOP_K;

    const unsigned long long lmask = (1ull << lane) - 1ull;
    int cnt = 0;
#pragma unroll
    for (int s = 0; s < 64; ++s) {
        int g = (s >> 2) * 256 + lane * 4 + (s & 3);
        bool p = v[s] >= TK_THRESH;
        unsigned long long m = __ballot(p);
        if (p) {
            int pos = cnt + __popcll(m & lmask);
            if (pos < TK_CAP) {
                unsigned b  = __float_as_uint(v[s]);
                unsigned mo = b ^ (unsigned)(((int)b >> 31) | 0x80000000);
                cand[wave][pos] =
                    ((unsigned long long)mo << 32) | (unsigned)(N_NODES - 1 - g);
            }
        }
        cnt += __popcll(m);
    }

    if (cnt >= TOP_K && cnt <= TK_CAP) {
        for (int j = cnt + lane; j < TK_CAP; j += 64) cand[wave][j] = 0ull;
        unsigned long long c0 = cand[wave][lane], c1 = cand[wave][lane + 64];
        for (int r = 0; r < TOP_K; ++r) {
            unsigned long long b = c0 > c1 ? c0 : c1;
#pragma unroll
            for (int m = 1; m < 64; m <<= 1) {
                unsigned long long o = __shfl_xor(b, m);
                b = o > b ? o : b;
            }
            if (lane == 0) op[r] = N_NODES - 1 - (int)(unsigned)(b & 0xFFFFFFFFu);
            if (c0 == b) c0 = 0ull;
            if (c1 == b) c1 = 0ull;
        }
    } else {
        // exact fallback: 16 rounds of full wave-argmax with tie-break
        for (int r = 0; r < TOP_K; ++r) {
            float bv = -INFINITY; int bg = 0x7fffffff;
#pragma unroll
            for (int s = 0; s < 64; ++s) {
                int g = (s >> 2) * 256 + lane * 4 + (s & 3);
                bool better = (v[s] > bv) || (v[s] == bv && g < bg);
                bv = better ? v[s] : bv;
                bg = better ? g : bg;
            }
#pragma unroll
            for (int m = 1; m < 64; m <<= 1) {
                float ov = __shfl_xor(bv, m);
                int   og = __shfl_xor(bg, m);
                bool better = (ov > bv) || (ov == bv && og < bg);
                bv = better ? ov : bv;
                bg = better ? og : bg;
            }
            if (lane == 0) op[r] = bg;
#pragma unroll
            for (int s = 0; s < 64; ++s) {
                int g = (s >> 2) * 256 + lane * 4 + (s & 3);
                if (g == bg) v[s] = -INFINITY;
            }
        }
    }
}

// ---------------------------------------------------------------------------
// Aggregate: softmax over 16 nbrs per head, gather-weighted sum, ELU.
// ---------------------------------------------------------------------------
__global__ __launch_bounds__(256) void aggregate_kernel(
    const float* __restrict__ Wh, const int* __restrict__ topk,
    const float* __restrict__ s_src, const float* __restrict__ s_dst,
    float* __restrict__ out)
{
    const int i = blockIdx.x, t = threadIdx.x;
    __shared__ int   sidx[TOP_K];
    __shared__ float salpha[TOP_K][NUM_HEADS];
    __shared__ float ssrc[NUM_HEADS];

    if (t < TOP_K) sidx[t] = topk[(size_t)i * TOP_K + t];
    if (t < NUM_HEADS) ssrc[t] = s_src[i * NUM_HEADS + t];
    __syncthreads();

    if (t < TOP_K * NUM_HEADS) {
        int m = t >> 2, h = t & 3;
        float e = ssrc[h] + s_dst[sidx[m] * NUM_HEADS + h];
        e = (e >= 0.f) ? e : NEG_SLOPE * e;
        salpha[m][h] = e;
    }
    __syncthreads();

    if (t < NUM_HEADS) {
        int h = t;
        float mx = -INFINITY;
#pragma unroll
        for (int m = 0; m < TOP_K; ++m) mx = fmaxf(mx, salpha[m][h]);
        float ex[TOP_K]; float sum = 0.f;
#pragma unroll
        for (int m = 0; m < TOP_K; ++m) { ex[m] = expf(salpha[m][h] - mx); sum += ex[m]; }
        float inv = 1.f / sum;
#pragma unroll
        for (int m = 0; m < TOP_K; ++m) salpha[m][h] = ex[m] * inv;
    }
    __syncthreads();

#pragma unroll
    for (int rep = 0; rep < 2; ++rep) {
        int c = rep * 256 + t;          // c = h*128 + d
        int h = c >> 7;
        float acc = 0.f;
#pragma unroll
        for (int m = 0; m < TOP_K; ++m)
            acc += salpha[m][h] * Wh[(size_t)sidx[m] * OUT_DIM + c];
        out[(size_t)i * OUT_DIM + c] = (acc > 0.f) ? acc : (expf(acc) - 1.f);
    }
}

// ---------------------------------------------------------------------------
extern "C" void kernel_launch(void* const* d_in, const int* in_sizes, int n_in,
                              void* d_out, int out_size, void* d_ws, size_t ws_size,
                              hipStream_t stream) {
    const float* x   = (const float*)d_in[0];
    const float* adj = (const float*)d_in[1];
    const float* W   = (const float*)d_in[2];
    const float* a   = (const float*)d_in[3];
    float* out = (float*)d_out;

    char* ws = (char*)d_ws;
    float*          Wh    = (float*)ws;                                  //  8 MB
    unsigned short* xc    = (unsigned short*)(ws + (8u << 20));          // 16 MB
    unsigned short* wc    = (unsigned short*)(ws + (24u << 20));         //  2 MB
    float*          s_src = (float*)(ws + (26u << 20));                  // 64 KB
    float*          s_dst = s_src + N_NODES * NUM_HEADS;                 // 64 KB
    int*            topkb = (int*)(s_dst + N_NODES * NUM_HEADS);         // 256 KB

    prep_kernel<<<(N_NODES * 128) / 256, 256, 0, stream>>>(x, xc);
    prep_kernel<<<(OUT_DIM * 128) / 256, 256, 0, stream>>>(W, wc);
    gemm_kernel<<<dim3(N_NODES / GBM, OUT_DIM / GBN), 512, 0, stream>>>(xc, wc, Wh);
    score_kernel<<<N_NODES, 256, 0, stream>>>(Wh, a, s_src, s_dst);
    topk_kernel<<<N_NODES / 4, 256, 0, stream>>>(adj, topkb);
    aggregate_kernel<<<N_NODES, 256, 0, stream>>>(Wh, topkb, s_src, s_dst, out);
}